// Round 9
// baseline (296.539 us; speedup 1.0000x reference)
//
#include <hip/hip_runtime.h>
#include <hip/hip_bf16.h>

// MaskedMSA: B=8, T=1024, C=768, H=12, D=64, M=8, N=8200
// R8: attn K-loop fully de-LDS'd. qkv writes V TRANSPOSED (b,h,d,t) via an
//     LDS-transpose epilogue; attn then loads K-frags (natural [key][d]) and
//     V-frags (transposed [d][t]) straight from global/L1 — both match MFMA
//     B-frag layout exactly. No staging, no barriers in the loop; 1-wave
//     blocks (grid 3072). Only wave-private Ps round-trip (4.6 KB) remains.

#define BB 8
#define TT 1024
#define CC 768
#define HH 12
#define DD 64
#define MM 8
#define NTOK (BB*TT)            // 8192
#define NX (NTOK*CC)            // 6291456
#define NWQ (3*CC*CC)           // 1769472
#define NWP (CC*CC)             // 589824
#define QSCALE 0.18033688011112042f   // 0.125 * log2(e)

typedef short bf16x8 __attribute__((ext_vector_type(8)));
typedef float f32x4  __attribute__((ext_vector_type(4)));
typedef float f32x16 __attribute__((ext_vector_type(16)));

__device__ __forceinline__ void gld16(const void* g, void* l) {
  __builtin_amdgcn_global_load_lds(
      (const __attribute__((address_space(1))) void*)g,
      (__attribute__((address_space(3))) void*)l, 16, 0, 0);
}

// RNE fp32->bf16
__device__ __forceinline__ short bf_rne(float f) {
  unsigned u = __float_as_uint(f);
  return (short)((u + 0x7FFFu + ((u >> 16) & 1u)) >> 16);
}
// RNE fp32->bf16 hi, residual -> bf16 lo
__device__ __forceinline__ short bf_split(float f, short& lo) {
  unsigned u = __float_as_uint(f);
  unsigned hb = (u + 0x7FFFu + ((u >> 16) & 1u)) >> 16;
  float r = f - __uint_as_float(hb << 16);
  lo = bf_rne(r);
  return (short)hb;
}

// ---------------- split: x,Wqkv -> bf16 hi; Wp -> bf16 hi+lo ----------------
__global__ __launch_bounds__(256) void split_inputs(
    const float* __restrict__ x, const float* __restrict__ wq,
    const float* __restrict__ wp,
    short* __restrict__ xh, short* __restrict__ wqh,
    short* __restrict__ wph, short* __restrict__ wpl) {
  const int G0 = NX/4, G1 = G0 + NWQ/4, G2 = G1 + NWP/4;
  int i = blockIdx.x * 256 + threadIdx.x;
  if (i >= G2) return;
  if (i < G1) {
    const float* src = (i < G0) ? x : wq;
    short* dh = (i < G0) ? xh : wqh;
    int li = (i < G0) ? i : i - G0;
    float4 v = *(const float4*)(src + (size_t)li * 4);
    short4 h;
    h.x = bf_rne(v.x); h.y = bf_rne(v.y); h.z = bf_rne(v.z); h.w = bf_rne(v.w);
    *(short4*)(dh + (size_t)li * 4) = h;
  } else {
    int li = i - G1;
    float4 v = *(const float4*)(wp + (size_t)li * 4);
    short4 h, l;
    h.x = bf_split(v.x, l.x);
    h.y = bf_split(v.y, l.y);
    h.z = bf_split(v.z, l.z);
    h.w = bf_split(v.w, l.w);
    *(short4*)(wph + (size_t)li * 4) = h;
    *(short4*)(wpl + (size_t)li * 4) = l;
  }
}

// ---------------- MFMA GEMM core (NT), 32x32x16; caller provides LDS --------
template<bool TRIPLE>
__device__ __forceinline__ void gemm_core_768(
    const short* __restrict__ ah_g, const short* __restrict__ al_g,
    const short* __restrict__ bh_g, const short* __restrict__ bl_g,
    short* Ah, short* Al, short* Bh, short* Bl,
    int m0, int n0, f32x16 (&acc)[2][2],
    int& wm_o, int& wn_o) {
  const int tid = threadIdx.x;
  const int w = tid >> 6, ln = tid & 63;
  const int wm = (w >> 1) * 64, wn = (w & 1) * 64;
  const int sr = ln >> 2, sc = (ln & 3) * 8;
  const int l31 = ln & 31, lhi = ln >> 5;
  const int c0 = 2*w, c1 = 2*w + 1;
  const short* gAh0 = ah_g + (size_t)(m0 + c0*16 + sr)*CC + sc;
  const short* gAh1 = ah_g + (size_t)(m0 + c1*16 + sr)*CC + sc;
  const short* gBh0 = bh_g + (size_t)(n0 + c0*16 + sr)*CC + sc;
  const short* gBh1 = bh_g + (size_t)(n0 + c1*16 + sr)*CC + sc;
  const short* gAl0 = TRIPLE ? al_g + (size_t)(m0 + c0*16 + sr)*CC + sc : nullptr;
  const short* gAl1 = TRIPLE ? al_g + (size_t)(m0 + c1*16 + sr)*CC + sc : nullptr;
  const short* gBl0 = TRIPLE ? bl_g + (size_t)(n0 + c0*16 + sr)*CC + sc : nullptr;
  const short* gBl1 = TRIPLE ? bl_g + (size_t)(n0 + c1*16 + sr)*CC + sc : nullptr;
  #pragma unroll
  for (int i = 0; i < 2; i++)
    #pragma unroll
    for (int j = 0; j < 2; j++)
      #pragma unroll
      for (int r = 0; r < 16; r++) acc[i][j][r] = 0.f;

  for (int it = 0; it < 24; ++it) {
    const int ko = it * 32;
    gld16(gAh0 + ko, &Ah[c0*512]);
    gld16(gAh1 + ko, &Ah[c1*512]);
    gld16(gBh0 + ko, &Bh[c0*512]);
    gld16(gBh1 + ko, &Bh[c1*512]);
    if constexpr (TRIPLE) {
      gld16(gAl0 + ko, &Al[c0*512]);
      gld16(gAl1 + ko, &Al[c1*512]);
      gld16(gBl0 + ko, &Bl[c0*512]);
      gld16(gBl1 + ko, &Bl[c1*512]);
    }
    __syncthreads();
    bf16x8 a_h[2][2], b_h[2][2];
    #pragma unroll
    for (int t = 0; t < 2; ++t)
      #pragma unroll
      for (int kc = 0; kc < 2; ++kc) {
        a_h[t][kc] = *(const bf16x8*)&Ah[(wm + t*32 + l31)*32 + kc*16 + lhi*8];
        b_h[t][kc] = *(const bf16x8*)&Bh[(wn + t*32 + l31)*32 + kc*16 + lhi*8];
      }
    if constexpr (TRIPLE) {
      bf16x8 a_l[2][2], b_l[2][2];
      #pragma unroll
      for (int t = 0; t < 2; ++t)
        #pragma unroll
        for (int kc = 0; kc < 2; ++kc) {
          a_l[t][kc] = *(const bf16x8*)&Al[(wm + t*32 + l31)*32 + kc*16 + lhi*8];
          b_l[t][kc] = *(const bf16x8*)&Bl[(wn + t*32 + l31)*32 + kc*16 + lhi*8];
        }
      #pragma unroll
      for (int mt = 0; mt < 2; ++mt)
        #pragma unroll
        for (int nt = 0; nt < 2; ++nt)
          #pragma unroll
          for (int kc = 0; kc < 2; ++kc) {
            acc[mt][nt] = __builtin_amdgcn_mfma_f32_32x32x16_bf16(
                a_h[mt][kc], b_h[nt][kc], acc[mt][nt], 0, 0, 0);
            acc[mt][nt] = __builtin_amdgcn_mfma_f32_32x32x16_bf16(
                a_h[mt][kc], b_l[nt][kc], acc[mt][nt], 0, 0, 0);
            acc[mt][nt] = __builtin_amdgcn_mfma_f32_32x32x16_bf16(
                a_l[mt][kc], b_h[nt][kc], acc[mt][nt], 0, 0, 0);
          }
    } else {
      #pragma unroll
      for (int mt = 0; mt < 2; ++mt)
        #pragma unroll
        for (int nt = 0; nt < 2; ++nt)
          #pragma unroll
          for (int kc = 0; kc < 2; ++kc)
            acc[mt][nt] = __builtin_amdgcn_mfma_f32_32x32x16_bf16(
                a_h[mt][kc], b_h[nt][kc], acc[mt][nt], 0, 0, 0);
    }
    __syncthreads();
  }
  wm_o = wm; wn_o = wn;
}

// QKV (single-pass bf16): q (prescaled) / k natural; V TRANSPOSED (b,h,d,t).
__global__ __launch_bounds__(256) void qkv_mfma(
    const short* __restrict__ ah_g, const short* __restrict__ bh_g,
    const int* __restrict__ mask,
    short* __restrict__ qb, short* __restrict__ kb, short* __restrict__ vbt) {
  __shared__ __align__(16) short SMEM[128*132];   // 33 KB: staging(16KB) / T
  const int m0 = blockIdx.y * 128, n0 = blockIdx.x * 128;
  f32x16 acc[2][2];
  int wm, wn;
  gemm_core_768<false>(ah_g, nullptr, bh_g, nullptr,
                       SMEM, SMEM, SMEM + 4096, SMEM + 4096, m0, n0, acc, wm, wn);
  const int tid = threadIdx.x, ln = tid & 63;
  const int l31 = ln & 31, lhi = ln >> 5;
  const int s = n0 / CC;
  const int nb = n0 % CC;
  if (s < 2) {
    short* dst = (s == 0) ? qb : kb;
    const float qs = (s == 0) ? QSCALE : 1.f;
    #pragma unroll
    for (int mt = 0; mt < 2; ++mt) {
      #pragma unroll
      for (int reg = 0; reg < 16; ++reg) {
        int row = m0 + wm + mt*32 + 4*lhi + (reg & 3) + 8*(reg >> 2);
        int mk = mask[row];
        int b = row >> 10, t = row & 1023;
        size_t rb = ((size_t)b * HH) * TT;
        #pragma unroll
        for (int nt = 0; nt < 2; ++nt) {
          int gnb = nb + wn + nt*32 + l31;
          int h = gnb >> 6, d = gnb & 63;
          float v = mk ? acc[mt][nt][reg] * qs : 0.f;
          dst[((rb + (size_t)h * TT) + t) * DD + d] = bf_rne(v);
        }
      }
    }
  } else {
    // V: LDS transpose T[col][row] then coalesced write to vbt (b,h,d,t).
    // (final gemm_core barrier guarantees staging reads are done)
    #pragma unroll
    for (int mt = 0; mt < 2; ++mt) {
      #pragma unroll
      for (int reg = 0; reg < 16; ++reg) {
        int rl = wm + mt*32 + 4*lhi + (reg & 3) + 8*(reg >> 2);
        int mk = mask[m0 + rl];
        #pragma unroll
        for (int nt = 0; nt < 2; ++nt) {
          int cl = wn + nt*32 + l31;
          SMEM[cl*132 + rl] = bf_rne(mk ? acc[mt][nt][reg] : 0.f);
        }
      }
    }
    __syncthreads();
    const int c = tid >> 1, half = tid & 1;
    const int h = (nb + c) >> 6, d = (nb + c) & 63;
    const int b = m0 >> 10, t0 = (m0 & 1023) + half*64;
    short* dstp = vbt + (((size_t)(b*HH + h)*DD + d)*TT) + t0;
    const short* srcp = &SMEM[c*132 + half*64];
    #pragma unroll
    for (int g = 0; g < 8; ++g)
      *(bf16x8*)(dstp + g*8) = *(const bf16x8*)(srcp + g*8);
  }
}

// Proj (bf16x3): add bias, mask, write to out rows M..M+8191.
__global__ __launch_bounds__(256) void proj_mfma(
    const short* __restrict__ ah_g, const short* __restrict__ al_g,
    const short* __restrict__ bh_g, const short* __restrict__ bl_g,
    const int* __restrict__ mask, const float* __restrict__ bp,
    float* __restrict__ out) {
  __shared__ __align__(16) short Ah[128*32], Al[128*32];
  __shared__ __align__(16) short Bh[128*32], Bl[128*32];
  const int m0 = blockIdx.y * 128, n0 = blockIdx.x * 128;
  f32x16 acc[2][2];
  int wm, wn;
  gemm_core_768<true>(ah_g, al_g, bh_g, bl_g, Ah, Al, Bh, Bl, m0, n0, acc, wm, wn);
  const int ln = threadIdx.x & 63;
  const int l31 = ln & 31, lhi = ln >> 5;
  #pragma unroll
  for (int mt = 0; mt < 2; ++mt) {
    #pragma unroll
    for (int reg = 0; reg < 16; ++reg) {
      int row = m0 + wm + mt*32 + 4*lhi + (reg & 3) + 8*(reg >> 2);
      int mk = mask[row];
      float* orow = out + (size_t)(MM + row) * CC;
      #pragma unroll
      for (int nt = 0; nt < 2; ++nt) {
        int gn = n0 + wn + nt*32 + l31;
        orow[gn] = mk ? acc[mt][nt][reg] + bp[gn] : 0.f;
      }
    }
  }
}

// ---------------- MFMA attention: 1 wave/block, no LDS staging, no barriers -
__global__ __launch_bounds__(64) void attn_mfma(
    const short* __restrict__ qb, const short* __restrict__ kb,
    const short* __restrict__ vbt, const int* __restrict__ mask,
    short* __restrict__ obh, short* __restrict__ obl) {
  __shared__ __align__(16) short Ps[32][72];
  const int ln = threadIdx.x;          // 0..63
  const int fl = ln & 15, fq = ln >> 4;
  const int bh = blockIdx.x >> 5;
  const int q0 = (blockIdx.x & 31) * 32;
  const int b = bh / HH, h = bh % HH;
  const size_t baseK = (size_t)bh * TT * DD;   // q,k natural (t,d)
  const size_t baseV = (size_t)bh * DD * TT;   // v transposed (d,t)

  bf16x8 qf[2][2];
  #pragma unroll
  for (int mt = 0; mt < 2; ++mt)
    #pragma unroll
    for (int kc = 0; kc < 2; ++kc)
      qf[mt][kc] = *(const bf16x8*)&qb[baseK +
          (size_t)(q0 + mt*16 + fl) * DD + kc*32 + fq*8];

  f32x4 oa[2][4];
  float lsum[2][4];
  {
    f32x4 z = {0.f, 0.f, 0.f, 0.f};
    #pragma unroll
    for (int mt = 0; mt < 2; ++mt) {
      #pragma unroll
      for (int nt = 0; nt < 4; ++nt) oa[mt][nt] = z;
      #pragma unroll
      for (int r = 0; r < 4; ++r) lsum[mt][r] = 0.f;
    }
  }

  for (int kt = 0; kt < 16; ++kt) {
    // S = Q K^T (exp2 domain; K natural rows are B-frags directly)
    f32x4 s[2][4];
    {
      f32x4 z = {0.f, 0.f, 0.f, 0.f};
      #pragma unroll
      for (int mt = 0; mt < 2; ++mt)
        #pragma unroll
        for (int nt = 0; nt < 4; ++nt) s[mt][nt] = z;
    }
    #pragma unroll
    for (int kc = 0; kc < 2; ++kc) {
      bf16x8 kf[4];
      #pragma unroll
      for (int nt = 0; nt < 4; ++nt)
        kf[nt] = *(const bf16x8*)&kb[baseK +
            (size_t)(kt*64 + nt*16 + fl) * DD + kc*32 + fq*8];
      #pragma unroll
      for (int mt = 0; mt < 2; ++mt)
        #pragma unroll
        for (int nt = 0; nt < 4; ++nt)
          s[mt][nt] = __builtin_amdgcn_mfma_f32_16x16x32_bf16(
              qf[mt][kc], kf[nt], s[mt][nt], 0, 0, 0);
    }

    // P = 2^S, RTZ bf16; lsum accumulates the SAME rounded value.
    #pragma unroll
    for (int mt = 0; mt < 2; ++mt)
      #pragma unroll
      for (int nt = 0; nt < 4; ++nt)
        #pragma unroll
        for (int r = 0; r < 4; ++r) {
          float p = __builtin_amdgcn_exp2f(s[mt][nt][r]);
          unsigned pu = __float_as_uint(p);
          lsum[mt][r] += __uint_as_float(pu & 0xFFFF0000u);
          Ps[mt*16 + fq*4 + r][nt*16 + fl] = (short)(pu >> 16);
        }

    bf16x8 pf[2][2];
    #pragma unroll
    for (int mt = 0; mt < 2; ++mt)
      #pragma unroll
      for (int kc = 0; kc < 2; ++kc)
        pf[mt][kc] = *(const bf16x8*)&Ps[mt*16 + fl][kc*32 + fq*8];

    // O += P V  (transposed V rows are B-frags directly)
    #pragma unroll
    for (int kc = 0; kc < 2; ++kc) {
      bf16x8 vf[4];
      #pragma unroll
      for (int nt = 0; nt < 4; ++nt)
        vf[nt] = *(const bf16x8*)&vbt[baseV +
            (size_t)(nt*16 + fl) * TT + kt*64 + kc*32 + fq*8];
      #pragma unroll
      for (int mt = 0; mt < 2; ++mt)
        #pragma unroll
        for (int nt = 0; nt < 4; ++nt)
          oa[mt][nt] = __builtin_amdgcn_mfma_f32_16x16x32_bf16(
              pf[mt][kc], vf[nt], oa[mt][nt], 0, 0, 0);
    }
  }

  #pragma unroll
  for (int mt = 0; mt < 2; ++mt)
    #pragma unroll
    for (int r = 0; r < 4; ++r) {
      float v = lsum[mt][r];
      v += __shfl_xor(v, 1);
      v += __shfl_xor(v, 2);
      v += __shfl_xor(v, 4);
      v += __shfl_xor(v, 8);
      lsum[mt][r] = v;
    }

  #pragma unroll
  for (int mt = 0; mt < 2; ++mt)
    #pragma unroll
    for (int r = 0; r < 4; ++r) {
      int tok = b * TT + q0 + mt*16 + fq*4 + r;
      int mk = mask[tok];
      float inv = 1.f / lsum[mt][r];
      size_t ro = (size_t)tok * CC + h * DD;
      #pragma unroll
      for (int nt = 0; nt < 4; ++nt) {
        float v = mk ? oa[mt][nt][r] * inv : 0.f;
        short lo, hi = bf_split(v, lo);
        obh[ro + nt*16 + fl] = hi;
        obl[ro + nt*16 + fl] = lo;
      }
    }
}

__global__ void zero_head(float* __restrict__ out) {
  int i = blockIdx.x * 256 + threadIdx.x;
  if (i < MM * CC) out[i] = 0.f;
}

extern "C" void kernel_launch(void* const* d_in, const int* in_sizes, int n_in,
                              void* d_out, int out_size, void* d_ws, size_t ws_size,
                              hipStream_t stream) {
  const float* feats = (const float*)d_in[0];
  const int*   mask  = (const int*)d_in[1];
  const float* Wqkv  = (const float*)d_in[2];
  const float* Wp    = (const float*)d_in[3];
  const float* bp    = (const float*)d_in[4];
  float* out = (float*)d_out;

  short* qb   = (short*)d_ws;            // bf16 (b,h,t,d)
  short* kb   = qb + NX;                 // bf16 (b,h,t,d)
  short* vbt  = kb + NX;                 // bf16 (b,h,d,t)  TRANSPOSED
  short* S_hi = vbt + NX;                // x_hi, reused as o_hi after qkv
  short* S_lo = S_hi + NX;               // o_lo (attention epilogue)
  short* wqh  = S_lo + NX;
  short* wph  = wqh + NWQ;
  short* wpl  = wph + NWP;

  const int G2 = (NX + NWQ + NWP) / 4;
  split_inputs<<<dim3((G2 + 255)/256), dim3(256), 0, stream>>>(
      feats + (size_t)MM * CC, Wqkv, Wp, S_hi, wqh, wph, wpl);
  qkv_mfma<<<dim3(3*CC/128, NTOK/128), dim3(256), 0, stream>>>(
      S_hi, wqh, mask, qb, kb, vbt);
  attn_mfma<<<dim3(BB*HH*(TT/32)), dim3(64), 0, stream>>>(
      qb, kb, vbt, mask, S_hi, S_lo);
  proj_mfma<<<dim3(CC/128, NTOK/128), dim3(256), 0, stream>>>(
      S_hi, S_lo, wph, wpl, mask, bp, out);
  zero_head<<<dim3((MM*CC + 255)/256), dim3(256), 0, stream>>>(out);
}

// Round 10
// 262.538 us; speedup vs baseline: 1.1295x; 1.1295x over previous
//
#include <hip/hip_runtime.h>
#include <hip/hip_bf16.h>

// MaskedMSA: B=8, T=1024, C=768, H=12, D=64, M=8, N=8200
// R9: attention back to 4-wave/128q LDS-staged blocks (R8's 1-wave global-frag
//     design was latency-bound: MfmaUtil 10%). Kept from R8: qkv writes V
//     TRANSPOSED (b,h,d,t), so V staging is now 2 coalesced loads + 2
//     ds_write_b128 (was 16 scalar transposing writes -> 3.9e6 conflicts).

#define BB 8
#define TT 1024
#define CC 768
#define HH 12
#define DD 64
#define MM 8
#define NTOK (BB*TT)            // 8192
#define NX (NTOK*CC)            // 6291456
#define NWQ (3*CC*CC)           // 1769472
#define NWP (CC*CC)             // 589824
#define QSCALE 0.18033688011112042f   // 0.125 * log2(e)

typedef short bf16x8 __attribute__((ext_vector_type(8)));
typedef float f32x4  __attribute__((ext_vector_type(4)));
typedef float f32x16 __attribute__((ext_vector_type(16)));

__device__ __forceinline__ void gld16(const void* g, void* l) {
  __builtin_amdgcn_global_load_lds(
      (const __attribute__((address_space(1))) void*)g,
      (__attribute__((address_space(3))) void*)l, 16, 0, 0);
}

// RNE fp32->bf16
__device__ __forceinline__ short bf_rne(float f) {
  unsigned u = __float_as_uint(f);
  return (short)((u + 0x7FFFu + ((u >> 16) & 1u)) >> 16);
}
// RNE fp32->bf16 hi, residual -> bf16 lo
__device__ __forceinline__ short bf_split(float f, short& lo) {
  unsigned u = __float_as_uint(f);
  unsigned hb = (u + 0x7FFFu + ((u >> 16) & 1u)) >> 16;
  float r = f - __uint_as_float(hb << 16);
  lo = bf_rne(r);
  return (short)hb;
}

// ---------------- split: x,Wqkv -> bf16 hi; Wp -> bf16 hi+lo ----------------
__global__ __launch_bounds__(256) void split_inputs(
    const float* __restrict__ x, const float* __restrict__ wq,
    const float* __restrict__ wp,
    short* __restrict__ xh, short* __restrict__ wqh,
    short* __restrict__ wph, short* __restrict__ wpl) {
  const int G0 = NX/4, G1 = G0 + NWQ/4, G2 = G1 + NWP/4;
  int i = blockIdx.x * 256 + threadIdx.x;
  if (i >= G2) return;
  if (i < G1) {
    const float* src = (i < G0) ? x : wq;
    short* dh = (i < G0) ? xh : wqh;
    int li = (i < G0) ? i : i - G0;
    float4 v = *(const float4*)(src + (size_t)li * 4);
    short4 h;
    h.x = bf_rne(v.x); h.y = bf_rne(v.y); h.z = bf_rne(v.z); h.w = bf_rne(v.w);
    *(short4*)(dh + (size_t)li * 4) = h;
  } else {
    int li = i - G1;
    float4 v = *(const float4*)(wp + (size_t)li * 4);
    short4 h, l;
    h.x = bf_split(v.x, l.x);
    h.y = bf_split(v.y, l.y);
    h.z = bf_split(v.z, l.z);
    h.w = bf_split(v.w, l.w);
    *(short4*)(wph + (size_t)li * 4) = h;
    *(short4*)(wpl + (size_t)li * 4) = l;
  }
}

// ---------------- MFMA GEMM core (NT), 32x32x16; caller provides LDS --------
template<bool TRIPLE>
__device__ __forceinline__ void gemm_core_768(
    const short* __restrict__ ah_g, const short* __restrict__ al_g,
    const short* __restrict__ bh_g, const short* __restrict__ bl_g,
    short* Ah, short* Al, short* Bh, short* Bl,
    int m0, int n0, f32x16 (&acc)[2][2],
    int& wm_o, int& wn_o) {
  const int tid = threadIdx.x;
  const int w = tid >> 6, ln = tid & 63;
  const int wm = (w >> 1) * 64, wn = (w & 1) * 64;
  const int sr = ln >> 2, sc = (ln & 3) * 8;
  const int l31 = ln & 31, lhi = ln >> 5;
  const int c0 = 2*w, c1 = 2*w + 1;
  const short* gAh0 = ah_g + (size_t)(m0 + c0*16 + sr)*CC + sc;
  const short* gAh1 = ah_g + (size_t)(m0 + c1*16 + sr)*CC + sc;
  const short* gBh0 = bh_g + (size_t)(n0 + c0*16 + sr)*CC + sc;
  const short* gBh1 = bh_g + (size_t)(n0 + c1*16 + sr)*CC + sc;
  const short* gAl0 = TRIPLE ? al_g + (size_t)(m0 + c0*16 + sr)*CC + sc : nullptr;
  const short* gAl1 = TRIPLE ? al_g + (size_t)(m0 + c1*16 + sr)*CC + sc : nullptr;
  const short* gBl0 = TRIPLE ? bl_g + (size_t)(n0 + c0*16 + sr)*CC + sc : nullptr;
  const short* gBl1 = TRIPLE ? bl_g + (size_t)(n0 + c1*16 + sr)*CC + sc : nullptr;
  #pragma unroll
  for (int i = 0; i < 2; i++)
    #pragma unroll
    for (int j = 0; j < 2; j++)
      #pragma unroll
      for (int r = 0; r < 16; r++) acc[i][j][r] = 0.f;

  for (int it = 0; it < 24; ++it) {
    const int ko = it * 32;
    gld16(gAh0 + ko, &Ah[c0*512]);
    gld16(gAh1 + ko, &Ah[c1*512]);
    gld16(gBh0 + ko, &Bh[c0*512]);
    gld16(gBh1 + ko, &Bh[c1*512]);
    if constexpr (TRIPLE) {
      gld16(gAl0 + ko, &Al[c0*512]);
      gld16(gAl1 + ko, &Al[c1*512]);
      gld16(gBl0 + ko, &Bl[c0*512]);
      gld16(gBl1 + ko, &Bl[c1*512]);
    }
    __syncthreads();
    bf16x8 a_h[2][2], b_h[2][2];
    #pragma unroll
    for (int t = 0; t < 2; ++t)
      #pragma unroll
      for (int kc = 0; kc < 2; ++kc) {
        a_h[t][kc] = *(const bf16x8*)&Ah[(wm + t*32 + l31)*32 + kc*16 + lhi*8];
        b_h[t][kc] = *(const bf16x8*)&Bh[(wn + t*32 + l31)*32 + kc*16 + lhi*8];
      }
    if constexpr (TRIPLE) {
      bf16x8 a_l[2][2], b_l[2][2];
      #pragma unroll
      for (int t = 0; t < 2; ++t)
        #pragma unroll
        for (int kc = 0; kc < 2; ++kc) {
          a_l[t][kc] = *(const bf16x8*)&Al[(wm + t*32 + l31)*32 + kc*16 + lhi*8];
          b_l[t][kc] = *(const bf16x8*)&Bl[(wn + t*32 + l31)*32 + kc*16 + lhi*8];
        }
      #pragma unroll
      for (int mt = 0; mt < 2; ++mt)
        #pragma unroll
        for (int nt = 0; nt < 2; ++nt)
          #pragma unroll
          for (int kc = 0; kc < 2; ++kc) {
            acc[mt][nt] = __builtin_amdgcn_mfma_f32_32x32x16_bf16(
                a_h[mt][kc], b_h[nt][kc], acc[mt][nt], 0, 0, 0);
            acc[mt][nt] = __builtin_amdgcn_mfma_f32_32x32x16_bf16(
                a_h[mt][kc], b_l[nt][kc], acc[mt][nt], 0, 0, 0);
            acc[mt][nt] = __builtin_amdgcn_mfma_f32_32x32x16_bf16(
                a_l[mt][kc], b_h[nt][kc], acc[mt][nt], 0, 0, 0);
          }
    } else {
      #pragma unroll
      for (int mt = 0; mt < 2; ++mt)
        #pragma unroll
        for (int nt = 0; nt < 2; ++nt)
          #pragma unroll
          for (int kc = 0; kc < 2; ++kc)
            acc[mt][nt] = __builtin_amdgcn_mfma_f32_32x32x16_bf16(
                a_h[mt][kc], b_h[nt][kc], acc[mt][nt], 0, 0, 0);
    }
    __syncthreads();
  }
  wm_o = wm; wn_o = wn;
}

// QKV (single-pass bf16): q (prescaled) / k natural; V TRANSPOSED (b,h,d,t).
__global__ __launch_bounds__(256) void qkv_mfma(
    const short* __restrict__ ah_g, const short* __restrict__ bh_g,
    const int* __restrict__ mask,
    short* __restrict__ qb, short* __restrict__ kb, short* __restrict__ vbt) {
  __shared__ __align__(16) short SMEM[128*132];   // 33 KB: staging(16KB) / T
  const int m0 = blockIdx.y * 128, n0 = blockIdx.x * 128;
  f32x16 acc[2][2];
  int wm, wn;
  gemm_core_768<false>(ah_g, nullptr, bh_g, nullptr,
                       SMEM, SMEM, SMEM + 4096, SMEM + 4096, m0, n0, acc, wm, wn);
  const int tid = threadIdx.x, ln = tid & 63;
  const int l31 = ln & 31, lhi = ln >> 5;
  const int s = n0 / CC;
  const int nb = n0 % CC;
  if (s < 2) {
    short* dst = (s == 0) ? qb : kb;
    const float qs = (s == 0) ? QSCALE : 1.f;
    #pragma unroll
    for (int mt = 0; mt < 2; ++mt) {
      #pragma unroll
      for (int reg = 0; reg < 16; ++reg) {
        int row = m0 + wm + mt*32 + 4*lhi + (reg & 3) + 8*(reg >> 2);
        int mk = mask[row];
        int b = row >> 10, t = row & 1023;
        size_t rb = ((size_t)b * HH) * TT;
        #pragma unroll
        for (int nt = 0; nt < 2; ++nt) {
          int gnb = nb + wn + nt*32 + l31;
          int h = gnb >> 6, d = gnb & 63;
          float v = mk ? acc[mt][nt][reg] * qs : 0.f;
          dst[((rb + (size_t)h * TT) + t) * DD + d] = bf_rne(v);
        }
      }
    }
  } else {
    // V: LDS transpose T[col][row] then coalesced write to vbt (b,h,d,t).
    #pragma unroll
    for (int mt = 0; mt < 2; ++mt) {
      #pragma unroll
      for (int reg = 0; reg < 16; ++reg) {
        int rl = wm + mt*32 + 4*lhi + (reg & 3) + 8*(reg >> 2);
        int mk = mask[m0 + rl];
        #pragma unroll
        for (int nt = 0; nt < 2; ++nt) {
          int cl = wn + nt*32 + l31;
          SMEM[cl*132 + rl] = bf_rne(mk ? acc[mt][nt][reg] : 0.f);
        }
      }
    }
    __syncthreads();
    const int c = tid >> 1, half = tid & 1;
    const int h = (nb + c) >> 6, d = (nb + c) & 63;
    const int b = m0 >> 10, t0 = (m0 & 1023) + half*64;
    short* dstp = vbt + (((size_t)(b*HH + h)*DD + d)*TT) + t0;
    const short* srcp = &SMEM[c*132 + half*64];
    #pragma unroll
    for (int g = 0; g < 8; ++g)
      *(bf16x8*)(dstp + g*8) = *(const bf16x8*)(srcp + g*8);
  }
}

// Proj (bf16x3): add bias, mask, write to out rows M..M+8191.
__global__ __launch_bounds__(256) void proj_mfma(
    const short* __restrict__ ah_g, const short* __restrict__ al_g,
    const short* __restrict__ bh_g, const short* __restrict__ bl_g,
    const int* __restrict__ mask, const float* __restrict__ bp,
    float* __restrict__ out) {
  __shared__ __align__(16) short Ah[128*32], Al[128*32];
  __shared__ __align__(16) short Bh[128*32], Bl[128*32];
  const int m0 = blockIdx.y * 128, n0 = blockIdx.x * 128;
  f32x16 acc[2][2];
  int wm, wn;
  gemm_core_768<true>(ah_g, al_g, bh_g, bl_g, Ah, Al, Bh, Bl, m0, n0, acc, wm, wn);
  const int ln = threadIdx.x & 63;
  const int l31 = ln & 31, lhi = ln >> 5;
  #pragma unroll
  for (int mt = 0; mt < 2; ++mt) {
    #pragma unroll
    for (int reg = 0; reg < 16; ++reg) {
      int row = m0 + wm + mt*32 + 4*lhi + (reg & 3) + 8*(reg >> 2);
      int mk = mask[row];
      float* orow = out + (size_t)(MM + row) * CC;
      #pragma unroll
      for (int nt = 0; nt < 2; ++nt) {
        int gn = n0 + wn + nt*32 + l31;
        orow[gn] = mk ? acc[mt][nt][reg] + bp[gn] : 0.f;
      }
    }
  }
}

// ---------------- MFMA flash attention: 4 waves/128q, LDS-staged K & Vt -----
__global__ __launch_bounds__(256) void attn_mfma(
    const short* __restrict__ qb, const short* __restrict__ kb,
    const short* __restrict__ vbt, const int* __restrict__ mask,
    short* __restrict__ obh, short* __restrict__ obl) {
  __shared__ __align__(16) short Ks[64][72];       // [key][d]
  __shared__ __align__(16) short Vt[64][72];       // [d][key]
  __shared__ __align__(16) short Ps[4][32][72];    // per-wave P
  const int tid = threadIdx.x, w = tid >> 6, ln = tid & 63;
  const int fl = ln & 15, fq = ln >> 4;
  const int bh = blockIdx.x >> 3;
  const int q0 = (blockIdx.x & 7) * 128;
  const int b = bh / HH, h = bh % HH;
  const size_t baseK = (size_t)bh * TT * DD;   // q,k natural (t,d)
  const size_t baseV = (size_t)bh * DD * TT;   // v transposed (d,t)

  bf16x8 qf[2][2];
  #pragma unroll
  for (int mt = 0; mt < 2; ++mt)
    #pragma unroll
    for (int kc = 0; kc < 2; ++kc)
      qf[mt][kc] = *(const bf16x8*)&qb[baseK +
          (size_t)(q0 + w*32 + mt*16 + fl) * DD + kc*32 + fq*8];

  f32x4 oa[2][4];
  float lsum[2][4];
  {
    f32x4 z = {0.f, 0.f, 0.f, 0.f};
    #pragma unroll
    for (int mt = 0; mt < 2; ++mt) {
      #pragma unroll
      for (int nt = 0; nt < 4; ++nt) oa[mt][nt] = z;
      #pragma unroll
      for (int r = 0; r < 4; ++r) lsum[mt][r] = 0.f;
    }
  }

  const int srow = tid >> 2, scol = (tid & 3) * 16;  // staging: 32B/thread

  for (int kt = 0; kt < 16; ++kt) {
    __syncthreads();
    {
      // K tile natural [key][d] from kb
      const short* kg = &kb[baseK + (size_t)(kt*64 + srow) * DD + scol];
      bf16x8 k0 = *(const bf16x8*)kg;
      bf16x8 k1 = *(const bf16x8*)(kg + 8);
      *(bf16x8*)&Ks[srow][scol] = k0;
      *(bf16x8*)&Ks[srow][scol + 8] = k1;
      // V tile [d][key] from transposed vbt (coalesced rows)
      const short* vg = &vbt[baseV + (size_t)srow * TT + kt*64 + scol];
      bf16x8 v0 = *(const bf16x8*)vg;
      bf16x8 v1 = *(const bf16x8*)(vg + 8);
      *(bf16x8*)&Vt[srow][scol] = v0;
      *(bf16x8*)&Vt[srow][scol + 8] = v1;
    }
    __syncthreads();

    bf16x8 kf[4][2], vf[4][2];
    #pragma unroll
    for (int nt = 0; nt < 4; ++nt)
      #pragma unroll
      for (int kc = 0; kc < 2; ++kc) {
        kf[nt][kc] = *(const bf16x8*)&Ks[nt*16 + fl][kc*32 + fq*8];
        vf[nt][kc] = *(const bf16x8*)&Vt[nt*16 + fl][kc*32 + fq*8];
      }

    f32x4 s[2][4];
    {
      f32x4 z = {0.f, 0.f, 0.f, 0.f};
      #pragma unroll
      for (int mt = 0; mt < 2; ++mt)
        #pragma unroll
        for (int nt = 0; nt < 4; ++nt) s[mt][nt] = z;
    }
    #pragma unroll
    for (int mt = 0; mt < 2; ++mt)
      #pragma unroll
      for (int nt = 0; nt < 4; ++nt) {
        s[mt][nt] = __builtin_amdgcn_mfma_f32_16x16x32_bf16(
            qf[mt][0], kf[nt][0], s[mt][nt], 0, 0, 0);
        s[mt][nt] = __builtin_amdgcn_mfma_f32_16x16x32_bf16(
            qf[mt][1], kf[nt][1], s[mt][nt], 0, 0, 0);
      }

    // P = 2^S, RTZ bf16; lsum accumulates the SAME rounded value.
    #pragma unroll
    for (int mt = 0; mt < 2; ++mt)
      #pragma unroll
      for (int nt = 0; nt < 4; ++nt)
        #pragma unroll
        for (int r = 0; r < 4; ++r) {
          float p = __builtin_amdgcn_exp2f(s[mt][nt][r]);
          unsigned pu = __float_as_uint(p);
          lsum[mt][r] += __uint_as_float(pu & 0xFFFF0000u);
          Ps[w][mt*16 + fq*4 + r][nt*16 + fl] = (short)(pu >> 16);
        }

    bf16x8 pf[2][2];
    #pragma unroll
    for (int mt = 0; mt < 2; ++mt)
      #pragma unroll
      for (int kc = 0; kc < 2; ++kc)
        pf[mt][kc] = *(const bf16x8*)&Ps[w][mt*16 + fl][kc*32 + fq*8];

    #pragma unroll
    for (int mt = 0; mt < 2; ++mt)
      #pragma unroll
      for (int nt = 0; nt < 4; ++nt) {
        oa[mt][nt] = __builtin_amdgcn_mfma_f32_16x16x32_bf16(
            pf[mt][0], vf[nt][0], oa[mt][nt], 0, 0, 0);
        oa[mt][nt] = __builtin_amdgcn_mfma_f32_16x16x32_bf16(
            pf[mt][1], vf[nt][1], oa[mt][nt], 0, 0, 0);
      }
  }

  #pragma unroll
  for (int mt = 0; mt < 2; ++mt)
    #pragma unroll
    for (int r = 0; r < 4; ++r) {
      float v = lsum[mt][r];
      v += __shfl_xor(v, 1);
      v += __shfl_xor(v, 2);
      v += __shfl_xor(v, 4);
      v += __shfl_xor(v, 8);
      lsum[mt][r] = v;
    }

  #pragma unroll
  for (int mt = 0; mt < 2; ++mt)
    #pragma unroll
    for (int r = 0; r < 4; ++r) {
      int tok = b * TT + q0 + w*32 + mt*16 + fq*4 + r;
      int mk = mask[tok];
      float inv = 1.f / lsum[mt][r];
      size_t ro = (size_t)tok * CC + h * DD;
      #pragma unroll
      for (int nt = 0; nt < 4; ++nt) {
        float v = mk ? oa[mt][nt][r] * inv : 0.f;
        short lo, hi = bf_split(v, lo);
        obh[ro + nt*16 + fl] = hi;
        obl[ro + nt*16 + fl] = lo;
      }
    }
}

__global__ void zero_head(float* __restrict__ out) {
  int i = blockIdx.x * 256 + threadIdx.x;
  if (i < MM * CC) out[i] = 0.f;
}

extern "C" void kernel_launch(void* const* d_in, const int* in_sizes, int n_in,
                              void* d_out, int out_size, void* d_ws, size_t ws_size,
                              hipStream_t stream) {
  const float* feats = (const float*)d_in[0];
  const int*   mask  = (const int*)d_in[1];
  const float* Wqkv  = (const float*)d_in[2];
  const float* Wp    = (const float*)d_in[3];
  const float* bp    = (const float*)d_in[4];
  float* out = (float*)d_out;

  short* qb   = (short*)d_ws;            // bf16 (b,h,t,d)
  short* kb   = qb + NX;                 // bf16 (b,h,t,d)
  short* vbt  = kb + NX;                 // bf16 (b,h,d,t)  TRANSPOSED
  short* S_hi = vbt + NX;                // x_hi, reused as o_hi after qkv
  short* S_lo = S_hi + NX;               // o_lo (attention epilogue)
  short* wqh  = S_lo + NX;
  short* wph  = wqh + NWQ;
  short* wpl  = wph + NWP;

  const int G2 = (NX + NWQ + NWP) / 4;
  split_inputs<<<dim3((G2 + 255)/256), dim3(256), 0, stream>>>(
      feats + (size_t)MM * CC, Wqkv, Wp, S_hi, wqh, wph, wpl);
  qkv_mfma<<<dim3(3*CC/128, NTOK/128), dim3(256), 0, stream>>>(
      S_hi, wqh, mask, qb, kb, vbt);
  attn_mfma<<<dim3(BB*HH*(TT/128)), dim3(256), 0, stream>>>(
      qb, kb, vbt, mask, S_hi, S_lo);
  proj_mfma<<<dim3(CC/128, NTOK/128), dim3(256), 0, stream>>>(
      S_hi, S_lo, wph, wpl, mask, bp, out);
  zero_head<<<dim3((MM*CC + 255)/256), dim3(256), 0, stream>>>(out);
}

// Round 11
// 250.777 us; speedup vs baseline: 1.1825x; 1.0469x over previous
//
#include <hip/hip_runtime.h>
#include <hip/hip_bf16.h>

// MaskedMSA: B=8, T=1024, C=768, H=12, D=64, M=8, N=8200
// R10: V^T for free — for the V third of qkv, call the same NT-GEMM core with
//      A/B swapped (A=Wv rows, B=x tokens): the accumulator holds V^T
//      natively and the epilogue writes vbt(b,h,d,t) coalesced with NO LDS
//      transpose and NO extra barrier. qkv LDS back to 16 KB (5 blocks/CU).
//      Also: zero_head folded into split_inputs (one fewer launch).

#define BB 8
#define TT 1024
#define CC 768
#define HH 12
#define DD 64
#define MM 8
#define NTOK (BB*TT)            // 8192
#define NX (NTOK*CC)            // 6291456
#define NWQ (3*CC*CC)           // 1769472
#define NWP (CC*CC)             // 589824
#define QSCALE 0.18033688011112042f   // 0.125 * log2(e)

typedef short bf16x8 __attribute__((ext_vector_type(8)));
typedef float f32x4  __attribute__((ext_vector_type(4)));
typedef float f32x16 __attribute__((ext_vector_type(16)));

__device__ __forceinline__ void gld16(const void* g, void* l) {
  __builtin_amdgcn_global_load_lds(
      (const __attribute__((address_space(1))) void*)g,
      (__attribute__((address_space(3))) void*)l, 16, 0, 0);
}

// RNE fp32->bf16
__device__ __forceinline__ short bf_rne(float f) {
  unsigned u = __float_as_uint(f);
  return (short)((u + 0x7FFFu + ((u >> 16) & 1u)) >> 16);
}
// RNE fp32->bf16 hi, residual -> bf16 lo
__device__ __forceinline__ short bf_split(float f, short& lo) {
  unsigned u = __float_as_uint(f);
  unsigned hb = (u + 0x7FFFu + ((u >> 16) & 1u)) >> 16;
  float r = f - __uint_as_float(hb << 16);
  lo = bf_rne(r);
  return (short)hb;
}

// ------- split: x,Wqkv -> bf16 hi; Wp -> bf16 hi+lo; also zero out head -----
__global__ __launch_bounds__(256) void split_inputs(
    const float* __restrict__ x, const float* __restrict__ wq,
    const float* __restrict__ wp,
    short* __restrict__ xh, short* __restrict__ wqh,
    short* __restrict__ wph, short* __restrict__ wpl,
    float* __restrict__ out) {
  const int G0 = NX/4, G1 = G0 + NWQ/4, G2 = G1 + NWP/4;
  int i = blockIdx.x * 256 + threadIdx.x;
  if (i < MM*CC/4) {   // zero the first M rows of out (6144 floats)
    float4 z = {0.f, 0.f, 0.f, 0.f};
    ((float4*)out)[i] = z;
  }
  if (i >= G2) return;
  if (i < G1) {
    const float* src = (i < G0) ? x : wq;
    short* dh = (i < G0) ? xh : wqh;
    int li = (i < G0) ? i : i - G0;
    float4 v = *(const float4*)(src + (size_t)li * 4);
    short4 h;
    h.x = bf_rne(v.x); h.y = bf_rne(v.y); h.z = bf_rne(v.z); h.w = bf_rne(v.w);
    *(short4*)(dh + (size_t)li * 4) = h;
  } else {
    int li = i - G1;
    float4 v = *(const float4*)(wp + (size_t)li * 4);
    short4 h, l;
    h.x = bf_split(v.x, l.x);
    h.y = bf_split(v.y, l.y);
    h.z = bf_split(v.z, l.z);
    h.w = bf_split(v.w, l.w);
    *(short4*)(wph + (size_t)li * 4) = h;
    *(short4*)(wpl + (size_t)li * 4) = l;
  }
}

// ---------------- MFMA GEMM core (NT), 32x32x16; caller provides LDS --------
template<bool TRIPLE>
__device__ __forceinline__ void gemm_core_768(
    const short* __restrict__ ah_g, const short* __restrict__ al_g,
    const short* __restrict__ bh_g, const short* __restrict__ bl_g,
    short* Ah, short* Al, short* Bh, short* Bl,
    int m0, int n0, f32x16 (&acc)[2][2],
    int& wm_o, int& wn_o) {
  const int tid = threadIdx.x;
  const int w = tid >> 6, ln = tid & 63;
  const int wm = (w >> 1) * 64, wn = (w & 1) * 64;
  const int sr = ln >> 2, sc = (ln & 3) * 8;
  const int l31 = ln & 31, lhi = ln >> 5;
  const int c0 = 2*w, c1 = 2*w + 1;
  const short* gAh0 = ah_g + (size_t)(m0 + c0*16 + sr)*CC + sc;
  const short* gAh1 = ah_g + (size_t)(m0 + c1*16 + sr)*CC + sc;
  const short* gBh0 = bh_g + (size_t)(n0 + c0*16 + sr)*CC + sc;
  const short* gBh1 = bh_g + (size_t)(n0 + c1*16 + sr)*CC + sc;
  const short* gAl0 = TRIPLE ? al_g + (size_t)(m0 + c0*16 + sr)*CC + sc : nullptr;
  const short* gAl1 = TRIPLE ? al_g + (size_t)(m0 + c1*16 + sr)*CC + sc : nullptr;
  const short* gBl0 = TRIPLE ? bl_g + (size_t)(n0 + c0*16 + sr)*CC + sc : nullptr;
  const short* gBl1 = TRIPLE ? bl_g + (size_t)(n0 + c1*16 + sr)*CC + sc : nullptr;
  #pragma unroll
  for (int i = 0; i < 2; i++)
    #pragma unroll
    for (int j = 0; j < 2; j++)
      #pragma unroll
      for (int r = 0; r < 16; r++) acc[i][j][r] = 0.f;

  for (int it = 0; it < 24; ++it) {
    const int ko = it * 32;
    gld16(gAh0 + ko, &Ah[c0*512]);
    gld16(gAh1 + ko, &Ah[c1*512]);
    gld16(gBh0 + ko, &Bh[c0*512]);
    gld16(gBh1 + ko, &Bh[c1*512]);
    if constexpr (TRIPLE) {
      gld16(gAl0 + ko, &Al[c0*512]);
      gld16(gAl1 + ko, &Al[c1*512]);
      gld16(gBl0 + ko, &Bl[c0*512]);
      gld16(gBl1 + ko, &Bl[c1*512]);
    }
    __syncthreads();
    bf16x8 a_h[2][2], b_h[2][2];
    #pragma unroll
    for (int t = 0; t < 2; ++t)
      #pragma unroll
      for (int kc = 0; kc < 2; ++kc) {
        a_h[t][kc] = *(const bf16x8*)&Ah[(wm + t*32 + l31)*32 + kc*16 + lhi*8];
        b_h[t][kc] = *(const bf16x8*)&Bh[(wn + t*32 + l31)*32 + kc*16 + lhi*8];
      }
    if constexpr (TRIPLE) {
      bf16x8 a_l[2][2], b_l[2][2];
      #pragma unroll
      for (int t = 0; t < 2; ++t)
        #pragma unroll
        for (int kc = 0; kc < 2; ++kc) {
          a_l[t][kc] = *(const bf16x8*)&Al[(wm + t*32 + l31)*32 + kc*16 + lhi*8];
          b_l[t][kc] = *(const bf16x8*)&Bl[(wn + t*32 + l31)*32 + kc*16 + lhi*8];
        }
      #pragma unroll
      for (int mt = 0; mt < 2; ++mt)
        #pragma unroll
        for (int nt = 0; nt < 2; ++nt)
          #pragma unroll
          for (int kc = 0; kc < 2; ++kc) {
            acc[mt][nt] = __builtin_amdgcn_mfma_f32_32x32x16_bf16(
                a_h[mt][kc], b_h[nt][kc], acc[mt][nt], 0, 0, 0);
            acc[mt][nt] = __builtin_amdgcn_mfma_f32_32x32x16_bf16(
                a_h[mt][kc], b_l[nt][kc], acc[mt][nt], 0, 0, 0);
            acc[mt][nt] = __builtin_amdgcn_mfma_f32_32x32x16_bf16(
                a_l[mt][kc], b_h[nt][kc], acc[mt][nt], 0, 0, 0);
          }
    } else {
      #pragma unroll
      for (int mt = 0; mt < 2; ++mt)
        #pragma unroll
        for (int nt = 0; nt < 2; ++nt)
          #pragma unroll
          for (int kc = 0; kc < 2; ++kc)
            acc[mt][nt] = __builtin_amdgcn_mfma_f32_32x32x16_bf16(
                a_h[mt][kc], b_h[nt][kc], acc[mt][nt], 0, 0, 0);
    }
    __syncthreads();
  }
  wm_o = wm; wn_o = wn;
}

// QKV (single-pass bf16): q (prescaled) / k natural (b,h,t,d);
// V computed with SWAPPED operands -> acc holds V^T -> vbt (b,h,d,t) direct.
__global__ __launch_bounds__(256) void qkv_mfma(
    const short* __restrict__ xh, const short* __restrict__ wqh,
    const int* __restrict__ mask,
    short* __restrict__ qb, short* __restrict__ kb, short* __restrict__ vbt) {
  __shared__ __align__(16) short Ah[128*32], Bh[128*32];   // 16 KB
  const int m0 = blockIdx.y * 128, n0 = blockIdx.x * 128;
  const int s = n0 / CC;          // 0:q 1:k 2:v (128-blocks don't straddle)
  f32x16 acc[2][2];
  int wm, wn;
  const int ln = threadIdx.x & 63;
  const int l31 = ln & 31, lhi = ln >> 5;

  if (s < 2) {
    gemm_core_768<false>(xh, nullptr, wqh, nullptr,
                         Ah, nullptr, Bh, nullptr, m0, n0, acc, wm, wn);
    short* dst = (s == 0) ? qb : kb;
    const float qs = (s == 0) ? QSCALE : 1.f;
    const int nb = n0 % CC;
    #pragma unroll
    for (int mt = 0; mt < 2; ++mt) {
      #pragma unroll
      for (int reg = 0; reg < 16; ++reg) {
        int row = m0 + wm + mt*32 + 4*lhi + (reg & 3) + 8*(reg >> 2);
        int mk = mask[row];
        int b = row >> 10, t = row & 1023;
        size_t rb = ((size_t)b * HH) * TT;
        #pragma unroll
        for (int nt = 0; nt < 2; ++nt) {
          int gnb = nb + wn + nt*32 + l31;
          int h = gnb >> 6, d = gnb & 63;
          float v = mk ? acc[mt][nt][reg] * qs : 0.f;
          dst[((rb + (size_t)h * TT) + t) * DD + d] = bf_rne(v);
        }
      }
    }
  } else {
    // swapped: A = Wv rows (m0'=n0 absolute Wqkv row), B = x tokens (n0'=m0)
    gemm_core_768<false>(wqh, nullptr, xh, nullptr,
                         Ah, nullptr, Bh, nullptr, n0, m0, acc, wm, wn);
    const int b = m0 >> 10, t0 = m0 & 1023;
    #pragma unroll
    for (int mt = 0; mt < 2; ++mt) {
      #pragma unroll
      for (int reg = 0; reg < 16; ++reg) {
        int f = (n0 - 2*CC) + wm + mt*32 + 4*lhi + (reg & 3) + 8*(reg >> 2);
        int h = f >> 6, d = f & 63;
        short* drow = vbt + (((size_t)(b*HH + h)*DD) + d)*TT + t0;
        #pragma unroll
        for (int nt = 0; nt < 2; ++nt) {
          int tk = wn + nt*32 + l31;
          int mk = mask[m0 + tk];
          drow[tk] = bf_rne(mk ? acc[mt][nt][reg] : 0.f);
        }
      }
    }
  }
}

// Proj (bf16x3): add bias, mask, write to out rows M..M+8191.
__global__ __launch_bounds__(256) void proj_mfma(
    const short* __restrict__ ah_g, const short* __restrict__ al_g,
    const short* __restrict__ bh_g, const short* __restrict__ bl_g,
    const int* __restrict__ mask, const float* __restrict__ bp,
    float* __restrict__ out) {
  __shared__ __align__(16) short Ah[128*32], Al[128*32];
  __shared__ __align__(16) short Bh[128*32], Bl[128*32];
  const int m0 = blockIdx.y * 128, n0 = blockIdx.x * 128;
  f32x16 acc[2][2];
  int wm, wn;
  gemm_core_768<true>(ah_g, al_g, bh_g, bl_g, Ah, Al, Bh, Bl, m0, n0, acc, wm, wn);
  const int ln = threadIdx.x & 63;
  const int l31 = ln & 31, lhi = ln >> 5;
  #pragma unroll
  for (int mt = 0; mt < 2; ++mt) {
    #pragma unroll
    for (int reg = 0; reg < 16; ++reg) {
      int row = m0 + wm + mt*32 + 4*lhi + (reg & 3) + 8*(reg >> 2);
      int mk = mask[row];
      float* orow = out + (size_t)(MM + row) * CC;
      #pragma unroll
      for (int nt = 0; nt < 2; ++nt) {
        int gn = n0 + wn + nt*32 + l31;
        orow[gn] = mk ? acc[mt][nt][reg] + bp[gn] : 0.f;
      }
    }
  }
}

// ---------------- MFMA flash attention: 4 waves/128q, LDS-staged K & Vt -----
__global__ __launch_bounds__(256) void attn_mfma(
    const short* __restrict__ qb, const short* __restrict__ kb,
    const short* __restrict__ vbt, const int* __restrict__ mask,
    short* __restrict__ obh, short* __restrict__ obl) {
  __shared__ __align__(16) short Ks[64][72];       // [key][d]
  __shared__ __align__(16) short Vt[64][72];       // [d][key]
  __shared__ __align__(16) short Ps[4][32][72];    // per-wave P
  const int tid = threadIdx.x, w = tid >> 6, ln = tid & 63;
  const int fl = ln & 15, fq = ln >> 4;
  const int bh = blockIdx.x >> 3;
  const int q0 = (blockIdx.x & 7) * 128;
  const int b = bh / HH, h = bh % HH;
  const size_t baseK = (size_t)bh * TT * DD;   // q,k natural (t,d)
  const size_t baseV = (size_t)bh * DD * TT;   // v transposed (d,t)

  bf16x8 qf[2][2];
  #pragma unroll
  for (int mt = 0; mt < 2; ++mt)
    #pragma unroll
    for (int kc = 0; kc < 2; ++kc)
      qf[mt][kc] = *(const bf16x8*)&qb[baseK +
          (size_t)(q0 + w*32 + mt*16 + fl) * DD + kc*32 + fq*8];

  f32x4 oa[2][4];
  float lsum[2][4];
  {
    f32x4 z = {0.f, 0.f, 0.f, 0.f};
    #pragma unroll
    for (int mt = 0; mt < 2; ++mt) {
      #pragma unroll
      for (int nt = 0; nt < 4; ++nt) oa[mt][nt] = z;
      #pragma unroll
      for (int r = 0; r < 4; ++r) lsum[mt][r] = 0.f;
    }
  }

  const int srow = tid >> 2, scol = (tid & 3) * 16;  // staging: 32B/thread

  for (int kt = 0; kt < 16; ++kt) {
    __syncthreads();
    {
      const short* kg = &kb[baseK + (size_t)(kt*64 + srow) * DD + scol];
      bf16x8 k0 = *(const bf16x8*)kg;
      bf16x8 k1 = *(const bf16x8*)(kg + 8);
      *(bf16x8*)&Ks[srow][scol] = k0;
      *(bf16x8*)&Ks[srow][scol + 8] = k1;
      const short* vg = &vbt[baseV + (size_t)srow * TT + kt*64 + scol];
      bf16x8 v0 = *(const bf16x8*)vg;
      bf16x8 v1 = *(const bf16x8*)(vg + 8);
      *(bf16x8*)&Vt[srow][scol] = v0;
      *(bf16x8*)&Vt[srow][scol + 8] = v1;
    }
    __syncthreads();

    bf16x8 kf[4][2], vf[4][2];
    #pragma unroll
    for (int nt = 0; nt < 4; ++nt)
      #pragma unroll
      for (int kc = 0; kc < 2; ++kc) {
        kf[nt][kc] = *(const bf16x8*)&Ks[nt*16 + fl][kc*32 + fq*8];
        vf[nt][kc] = *(const bf16x8*)&Vt[nt*16 + fl][kc*32 + fq*8];
      }

    f32x4 s[2][4];
    {
      f32x4 z = {0.f, 0.f, 0.f, 0.f};
      #pragma unroll
      for (int mt = 0; mt < 2; ++mt)
        #pragma unroll
        for (int nt = 0; nt < 4; ++nt) s[mt][nt] = z;
    }
    #pragma unroll
    for (int mt = 0; mt < 2; ++mt)
      #pragma unroll
      for (int nt = 0; nt < 4; ++nt) {
        s[mt][nt] = __builtin_amdgcn_mfma_f32_16x16x32_bf16(
            qf[mt][0], kf[nt][0], s[mt][nt], 0, 0, 0);
        s[mt][nt] = __builtin_amdgcn_mfma_f32_16x16x32_bf16(
            qf[mt][1], kf[nt][1], s[mt][nt], 0, 0, 0);
      }

    // P = 2^S, RTZ bf16; lsum accumulates the SAME rounded value.
    #pragma unroll
    for (int mt = 0; mt < 2; ++mt)
      #pragma unroll
      for (int nt = 0; nt < 4; ++nt)
        #pragma unroll
        for (int r = 0; r < 4; ++r) {
          float p = __builtin_amdgcn_exp2f(s[mt][nt][r]);
          unsigned pu = __float_as_uint(p);
          lsum[mt][r] += __uint_as_float(pu & 0xFFFF0000u);
          Ps[w][mt*16 + fq*4 + r][nt*16 + fl] = (short)(pu >> 16);
        }

    bf16x8 pf[2][2];
    #pragma unroll
    for (int mt = 0; mt < 2; ++mt)
      #pragma unroll
      for (int kc = 0; kc < 2; ++kc)
        pf[mt][kc] = *(const bf16x8*)&Ps[w][mt*16 + fl][kc*32 + fq*8];

    #pragma unroll
    for (int mt = 0; mt < 2; ++mt)
      #pragma unroll
      for (int nt = 0; nt < 4; ++nt) {
        oa[mt][nt] = __builtin_amdgcn_mfma_f32_16x16x32_bf16(
            pf[mt][0], vf[nt][0], oa[mt][nt], 0, 0, 0);
        oa[mt][nt] = __builtin_amdgcn_mfma_f32_16x16x32_bf16(
            pf[mt][1], vf[nt][1], oa[mt][nt], 0, 0, 0);
      }
  }

  #pragma unroll
  for (int mt = 0; mt < 2; ++mt)
    #pragma unroll
    for (int r = 0; r < 4; ++r) {
      float v = lsum[mt][r];
      v += __shfl_xor(v, 1);
      v += __shfl_xor(v, 2);
      v += __shfl_xor(v, 4);
      v += __shfl_xor(v, 8);
      lsum[mt][r] = v;
    }

  #pragma unroll
  for (int mt = 0; mt < 2; ++mt)
    #pragma unroll
    for (int r = 0; r < 4; ++r) {
      int tok = b * TT + q0 + w*32 + mt*16 + fq*4 + r;
      int mk = mask[tok];
      float inv = 1.f / lsum[mt][r];
      size_t ro = (size_t)tok * CC + h * DD;
      #pragma unroll
      for (int nt = 0; nt < 4; ++nt) {
        float v = mk ? oa[mt][nt][r] * inv : 0.f;
        short lo, hi = bf_split(v, lo);
        obh[ro + nt*16 + fl] = hi;
        obl[ro + nt*16 + fl] = lo;
      }
    }
}

extern "C" void kernel_launch(void* const* d_in, const int* in_sizes, int n_in,
                              void* d_out, int out_size, void* d_ws, size_t ws_size,
                              hipStream_t stream) {
  const float* feats = (const float*)d_in[0];
  const int*   mask  = (const int*)d_in[1];
  const float* Wqkv  = (const float*)d_in[2];
  const float* Wp    = (const float*)d_in[3];
  const float* bp    = (const float*)d_in[4];
  float* out = (float*)d_out;

  short* qb   = (short*)d_ws;            // bf16 (b,h,t,d)
  short* kb   = qb + NX;                 // bf16 (b,h,t,d)
  short* vbt  = kb + NX;                 // bf16 (b,h,d,t)  TRANSPOSED
  short* S_hi = vbt + NX;                // x_hi, reused as o_hi after qkv
  short* S_lo = S_hi + NX;               // o_lo (attention epilogue)
  short* wqh  = S_lo + NX;
  short* wph  = wqh + NWQ;
  short* wpl  = wph + NWP;

  const int G2 = (NX + NWQ + NWP) / 4;
  split_inputs<<<dim3((G2 + 255)/256), dim3(256), 0, stream>>>(
      feats + (size_t)MM * CC, Wqkv, Wp, S_hi, wqh, wph, wpl, out);
  qkv_mfma<<<dim3(3*CC/128, NTOK/128), dim3(256), 0, stream>>>(
      S_hi, wqh, mask, qb, kb, vbt);
  attn_mfma<<<dim3(BB*HH*(TT/128)), dim3(256), 0, stream>>>(
      qb, kb, vbt, mask, S_hi, S_lo);
  proj_mfma<<<dim3(CC/128, NTOK/128), dim3(256), 0, stream>>>(
      S_hi, S_lo, wph, wpl, mask, bp, out);
}